// Round 1
// baseline (265.090 us; speedup 1.0000x reference)
//
#include <hip/hip_runtime.h>
#include <hip/hip_bf16.h>
#include <stdint.h>

#define E_ 8
#define K_ 2
#define D_ 768
#define O_ 3072
#define N_ 2048   // B*S = 4*512

typedef __attribute__((ext_vector_type(8))) __bf16 bf16x8;
typedef __attribute__((ext_vector_type(4))) float f32x4;

// round-to-nearest-even fp32 -> bf16 bits
__device__ __forceinline__ unsigned short f2bf(float f) {
    union { float f; uint32_t u; } a; a.f = f;
    uint32_t u = a.u;
    uint32_t r = (u + 0x7fffu + ((u >> 16) & 1u)) >> 16;
    return (unsigned short)r;
}

// ---------------- gating: 1 wave per token ----------------
__global__ __launch_bounds__(256) void gating_kernel(
    const float* __restrict__ x, const float* __restrict__ w_gate,
    int* __restrict__ counts, int* __restrict__ pair_token,
    float* __restrict__ pair_gate)
{
    int wid  = threadIdx.x >> 6;
    int lane = threadIdx.x & 63;
    int n = blockIdx.x * 4 + wid;
    if (n >= N_) return;
    const float* xr = x + (size_t)n * D_;

    float acc[E_];
#pragma unroll
    for (int e = 0; e < E_; ++e) acc[e] = 0.f;

    for (int c = 0; c < D_ / 64; ++c) {
        int d = c * 64 + lane;
        float xv = xr[d];
        const float* wg = w_gate + (size_t)d * E_;
        float4 w0 = *(const float4*)(wg);
        float4 w1 = *(const float4*)(wg + 4);
        acc[0] += xv * w0.x; acc[1] += xv * w0.y;
        acc[2] += xv * w0.z; acc[3] += xv * w0.w;
        acc[4] += xv * w1.x; acc[5] += xv * w1.y;
        acc[6] += xv * w1.z; acc[7] += xv * w1.w;
    }
#pragma unroll
    for (int e = 0; e < E_; ++e) {
        float v = acc[e];
        for (int off = 32; off > 0; off >>= 1) v += __shfl_xor(v, off, 64);
        acc[e] = v;
    }
    if (lane == 0) {
        // top-2, lower index wins ties (matches lax.top_k)
        int i0 = 0; float v0 = acc[0];
#pragma unroll
        for (int e = 1; e < E_; ++e) if (acc[e] > v0) { v0 = acc[e]; i0 = e; }
        int i1 = -1; float v1 = -3.0e38f;
#pragma unroll
        for (int e = 0; e < E_; ++e) if (e != i0 && acc[e] > v1) { v1 = acc[e]; i1 = e; }
        float ex = expf(v1 - v0);
        float g0 = 1.f / (1.f + ex);
        float g1 = ex / (1.f + ex);
        int p0 = atomicAdd(&counts[i0], 1);
        pair_token[i0 * N_ + p0] = n; pair_gate[i0 * N_ + p0] = g0;
        int p1 = atomicAdd(&counts[i1], 1);
        pair_token[i1 * N_ + p1] = n; pair_gate[i1 * N_ + p1] = g1;
    }
}

// ---------------- loss ----------------
__global__ __launch_bounds__(256) void loss_kernel(
    const int* __restrict__ counts, const float* __restrict__ pair_gate,
    float* __restrict__ out_loss)
{
    __shared__ float s_imp[E_];
    int t = threadIdx.x;
    if (t < E_) s_imp[t] = 0.f;
    __syncthreads();
    int e = t >> 5, l = t & 31;
    int cnt = counts[e];
    float p = 0.f;
    for (int i = l; i < cnt; i += 32) p += pair_gate[e * N_ + i];
    atomicAdd(&s_imp[e], p);
    __syncthreads();
    if (t == 0) {
        float mi = 0.f, ml = 0.f;
        float imp[E_], ld[E_];
#pragma unroll
        for (int i = 0; i < E_; ++i) {
            imp[i] = s_imp[i]; ld[i] = (float)counts[i];
            mi += imp[i]; ml += ld[i];
        }
        mi /= (float)E_; ml /= (float)E_;
        float vi = 0.f, vl = 0.f;
#pragma unroll
        for (int i = 0; i < E_; ++i) {
            vi += (imp[i] - mi) * (imp[i] - mi);
            vl += (ld[i] - ml) * (ld[i] - ml);
        }
        vi /= (float)(E_ - 1); vl /= (float)(E_ - 1);
        float loss = 0.01f * (vi / (mi * mi + 1e-10f) + vl / (ml * ml + 1e-10f));
        *out_loss = loss;
    }
}

// ---------------- x -> bf16 ----------------
__global__ __launch_bounds__(256) void cast_x_kernel(
    const float* __restrict__ x, unsigned short* __restrict__ xb)
{
    int i = blockIdx.x * 256 + threadIdx.x;           // float4 units
    float4 v = ((const float4*)x)[i];
    ushort4 o;
    o.x = f2bf(v.x); o.y = f2bf(v.y); o.z = f2bf(v.z); o.w = f2bf(v.w);
    ((ushort4*)xb)[i] = o;
}

// ---------------- Wb[e] = bf16(expert_w[e] + static_w) ----------------
__global__ __launch_bounds__(256) void prep_w_kernel(
    const float* __restrict__ ew, const float* __restrict__ sw,
    unsigned short* __restrict__ wb)
{
    int i = blockIdx.x * 256 + threadIdx.x;           // float4 units
    int f = i * 4;
    const int od = O_ * D_;
    int e = f / od;
    int rem = f - e * od;
    float4 a = *(const float4*)(ew + f);
    float4 b = *(const float4*)(sw + rem);
    ushort4 o;
    o.x = f2bf(a.x + b.x); o.y = f2bf(a.y + b.y);
    o.z = f2bf(a.z + b.z); o.w = f2bf(a.w + b.w);
    ((ushort4*)wb)[i] = o;
}

// ---------------- grouped GEMM ----------------
#define BM 64
#define BN 64
#define BK 64
#define LDT 72   // LDS row stride in bf16 elems (144 B: 16B-aligned, breaks 128B bank period)

__global__ __launch_bounds__(256) void moe_gemm_kernel(
    const unsigned short* __restrict__ xb,   // [N_, D_] bf16
    const unsigned short* __restrict__ wb,   // [E_, O_, D_] bf16
    const float* __restrict__ expert_b,      // [E_, O_]
    const int* __restrict__ counts,
    const int* __restrict__ pair_token,
    const float* __restrict__ pair_gate,
    float* __restrict__ y)                   // [N_, O_]
{
    int e = blockIdx.z;
    int cnt = counts[e];
    int m0 = blockIdx.y * BM;
    if (m0 >= cnt) return;
    int n0 = blockIdx.x * BN;

    __shared__ __align__(16) unsigned short sA[BM * LDT];
    __shared__ __align__(16) unsigned short sB[BN * LDT];

    int tid = threadIdx.x;
    int lane = tid & 63;
    int wid = tid >> 6;
    int wm = wid & 1, wn = wid >> 1;

    // Each thread stages 2x16B chunks of A and of B per K-tile.
    int tok[2];
#pragma unroll
    for (int s = 0; s < 2; ++s) {
        int c = tid + s * 256;
        int r = c >> 3;
        int mi = m0 + r;
        tok[s] = pair_token[e * N_ + (mi < cnt ? mi : 0)];
    }

    f32x4 acc[2][2];
#pragma unroll
    for (int a = 0; a < 2; ++a)
#pragma unroll
        for (int b = 0; b < 2; ++b) acc[a][b] = (f32x4){0.f, 0.f, 0.f, 0.f};

    const unsigned short* wbase = wb + (size_t)e * O_ * D_;
    int quad = lane >> 4;
    int l16 = lane & 15;

    for (int k0 = 0; k0 < D_; k0 += BK) {
#pragma unroll
        for (int s = 0; s < 2; ++s) {
            int c = tid + s * 256;
            int r = c >> 3;
            int kc = (c & 7) * 8;
            uint4 v = *(const uint4*)(xb + (size_t)tok[s] * D_ + k0 + kc);
            *(uint4*)(&sA[r * LDT + kc]) = v;
        }
#pragma unroll
        for (int s = 0; s < 2; ++s) {
            int c = tid + s * 256;
            int r = c >> 3;
            int kc = (c & 7) * 8;
            uint4 v = *(const uint4*)(wbase + (size_t)(n0 + r) * D_ + k0 + kc);
            *(uint4*)(&sB[r * LDT + kc]) = v;
        }
        __syncthreads();

#pragma unroll
        for (int kk = 0; kk < BK; kk += 32) {
            bf16x8 af[2], bfr[2];
#pragma unroll
            for (int mi2 = 0; mi2 < 2; ++mi2) {
                int row = wm * 32 + mi2 * 16 + l16;
                af[mi2] = *(const bf16x8*)(&sA[row * LDT + kk + quad * 8]);
            }
#pragma unroll
            for (int ni = 0; ni < 2; ++ni) {
                int rowb = wn * 32 + ni * 16 + l16;
                bfr[ni] = *(const bf16x8*)(&sB[rowb * LDT + kk + quad * 8]);
            }
#pragma unroll
            for (int mi2 = 0; mi2 < 2; ++mi2)
#pragma unroll
                for (int ni = 0; ni < 2; ++ni)
                    acc[mi2][ni] = __builtin_amdgcn_mfma_f32_16x16x32_bf16(
                        af[mi2], bfr[ni], acc[mi2][ni], 0, 0, 0);
        }
        __syncthreads();
    }

    // epilogue: y[token, o] += gate * (acc + b[e, o]) ; C/D map: col=lane&15, row=quad*4+reg
#pragma unroll
    for (int mi2 = 0; mi2 < 2; ++mi2) {
#pragma unroll
        for (int reg = 0; reg < 4; ++reg) {
            int rlocal = wm * 32 + mi2 * 16 + quad * 4 + reg;
            int mi = m0 + rlocal;
            if (mi < cnt) {
                int token = pair_token[e * N_ + mi];
                float gate = pair_gate[e * N_ + mi];
#pragma unroll
                for (int ni = 0; ni < 2; ++ni) {
                    int o = n0 + wn * 32 + ni * 16 + l16;
                    float v = gate * (acc[mi2][ni][reg] + expert_b[e * O_ + o]);
                    atomicAdd(&y[(size_t)token * O_ + o], v);
                }
            }
        }
    }
}

extern "C" void kernel_launch(void* const* d_in, const int* in_sizes, int n_in,
                              void* d_out, int out_size, void* d_ws, size_t ws_size,
                              hipStream_t stream) {
    const float* x        = (const float*)d_in[0];  // [4,512,768]
    const float* w_gate   = (const float*)d_in[1];  // [768,8]
    const float* expert_w = (const float*)d_in[2];  // [8,3072,768]
    const float* expert_b = (const float*)d_in[3];  // [8,3072]
    const float* static_w = (const float*)d_in[4];  // [3072,768]
    float* out = (float*)d_out;                     // y [N_,O_] then loss scalar

    char* ws = (char*)d_ws;
    int*   counts     = (int*)ws;                                  // 8 ints (pad 256)
    int*   pair_token = (int*)(ws + 256);                          // 8*2048 int
    float* pair_gate  = (float*)(ws + 256 + 65536);                // 8*2048 float
    unsigned short* xb = (unsigned short*)(ws + 256 + 131072);     // 3 MB
    unsigned short* wb = (unsigned short*)(ws + 256 + 131072 + 3145728); // 37.75 MB

    hipMemsetAsync(d_out, 0, (size_t)N_ * O_ * sizeof(float), stream);
    hipMemsetAsync(counts, 0, E_ * sizeof(int), stream);

    gating_kernel<<<N_ / 4, 256, 0, stream>>>(x, w_gate, counts, pair_token, pair_gate);
    loss_kernel<<<1, 256, 0, stream>>>(counts, pair_gate, out + (size_t)N_ * O_);
    cast_x_kernel<<<(N_ * D_ / 4) / 256, 256, 0, stream>>>(x, xb);
    prep_w_kernel<<<(E_ * O_ * D_ / 4) / 256, 256, 0, stream>>>(expert_w, static_w, wb);

    dim3 grid(O_ / BN, (N_ + BM - 1) / BM, E_);
    moe_gemm_kernel<<<grid, 256, 0, stream>>>(xb, wb, expert_b, counts,
                                              pair_token, pair_gate, out);
}

// Round 2
// 234.649 us; speedup vs baseline: 1.1297x; 1.1297x over previous
//
#include <hip/hip_runtime.h>
#include <hip/hip_bf16.h>
#include <stdint.h>

#define E_ 8
#define K_ 2
#define D_ 768
#define O_ 3072
#define N_ 2048   // B*S = 4*512

typedef __attribute__((ext_vector_type(8))) __bf16 bf16x8;
typedef __attribute__((ext_vector_type(4))) float f32x4;

// round-to-nearest-even fp32 -> bf16 bits
__device__ __forceinline__ unsigned short f2bf(float f) {
    union { float f; uint32_t u; } a; a.f = f;
    uint32_t u = a.u;
    uint32_t r = (u + 0x7fffu + ((u >> 16) & 1u)) >> 16;
    return (unsigned short)r;
}

__device__ __forceinline__ void async16(const void* g, void* l) {
    __builtin_amdgcn_global_load_lds(
        (const __attribute__((address_space(1))) void*)g,
        (__attribute__((address_space(3))) void*)l, 16, 0, 0);
}

// ---------------- gating: 1 wave per token; fused x->bf16 cast and y zeroing;
// token-major choice output (NO global atomics) ----------------
__global__ __launch_bounds__(256) void gating_kernel(
    const float* __restrict__ x, const float* __restrict__ w_gate,
    unsigned short* __restrict__ xb, int* __restrict__ choice_e,
    float* __restrict__ choice_g, float* __restrict__ y)
{
    int wid  = threadIdx.x >> 6;
    int lane = threadIdx.x & 63;
    int n = blockIdx.x * 4 + wid;
    const float* xr = x + (size_t)n * D_;

    float acc[E_];
#pragma unroll
    for (int e = 0; e < E_; ++e) acc[e] = 0.f;

    for (int c = 0; c < D_ / 64; ++c) {
        int d = c * 64 + lane;
        float xv = xr[d];
        xb[(size_t)n * D_ + d] = f2bf(xv);          // fused cast
        const float* wg = w_gate + (size_t)d * E_;
        float4 w0 = *(const float4*)(wg);
        float4 w1 = *(const float4*)(wg + 4);
        acc[0] += xv * w0.x; acc[1] += xv * w0.y;
        acc[2] += xv * w0.z; acc[3] += xv * w0.w;
        acc[4] += xv * w1.x; acc[5] += xv * w1.y;
        acc[6] += xv * w1.z; acc[7] += xv * w1.w;
    }
#pragma unroll
    for (int e = 0; e < E_; ++e) {
        float v = acc[e];
        for (int off = 32; off > 0; off >>= 1) v += __shfl_xor(v, off, 64);
        acc[e] = v;
    }
    if (lane == 0) {
        // top-2, lower index wins ties (matches lax.top_k)
        int i0 = 0; float v0 = acc[0];
#pragma unroll
        for (int e = 1; e < E_; ++e) if (acc[e] > v0) { v0 = acc[e]; i0 = e; }
        int i1 = -1; float v1 = -3.0e38f;
#pragma unroll
        for (int e = 0; e < E_; ++e) if (e != i0 && acc[e] > v1) { v1 = acc[e]; i1 = e; }
        float ex = expf(v1 - v0);
        float g0 = 1.f / (1.f + ex);
        float g1 = ex / (1.f + ex);
        choice_e[2 * n]     = i0;  choice_g[2 * n]     = g0;
        choice_e[2 * n + 1] = i1;  choice_g[2 * n + 1] = g1;
    }

    // fused y zeroing: 512 blocks x 12288 floats = N_*O_
    float4 z = {0.f, 0.f, 0.f, 0.f};
    float4* yb = (float4*)(y + (size_t)blockIdx.x * 12288);
#pragma unroll
    for (int i = 0; i < 12; ++i) yb[threadIdx.x + 256 * i] = z;
}

// ---------------- compact: build per-expert lists + loss (1 block) ----------------
__global__ __launch_bounds__(1024) void compact_kernel(
    const int* __restrict__ choice_e, const float* __restrict__ choice_g,
    int* __restrict__ counts, int* __restrict__ pair_token,
    float* __restrict__ pair_gate, float* __restrict__ out_loss)
{
    __shared__ int   s_cnt[E_];
    __shared__ float s_imp[E_];
    int t = threadIdx.x;
    if (t < E_) { s_cnt[t] = 0; s_imp[t] = 0.f; }
    __syncthreads();
    for (int i = t; i < N_ * 2; i += 1024) {
        int e = choice_e[i];
        float gv = choice_g[i];
        int pos = atomicAdd(&s_cnt[e], 1);
        pair_token[e * N_ + pos] = i >> 1;
        pair_gate[e * N_ + pos]  = gv;
        atomicAdd(&s_imp[e], gv);
    }
    __syncthreads();
    if (t < E_) counts[t] = s_cnt[t];
    if (t == 0) {
        float mi = 0.f, ml = 0.f, imp[E_], ld[E_];
#pragma unroll
        for (int i = 0; i < E_; ++i) {
            imp[i] = s_imp[i]; ld[i] = (float)s_cnt[i];
            mi += imp[i]; ml += ld[i];
        }
        mi /= (float)E_; ml /= (float)E_;
        float vi = 0.f, vl = 0.f;
#pragma unroll
        for (int i = 0; i < E_; ++i) {
            vi += (imp[i] - mi) * (imp[i] - mi);
            vl += (ld[i] - ml) * (ld[i] - ml);
        }
        vi /= (float)(E_ - 1); vl /= (float)(E_ - 1);
        *out_loss = 0.01f * (vi / (mi * mi + 1e-10f) + vl / (ml * ml + 1e-10f));
    }
}

// ---------------- Wb[e] = bf16(expert_w[e] + static_w) ----------------
__global__ __launch_bounds__(256) void prep_w_kernel(
    const float* __restrict__ ew, const float* __restrict__ sw,
    unsigned short* __restrict__ wb)
{
    int i = blockIdx.x * 256 + threadIdx.x;           // float4 units
    int f = i * 4;
    const int od = O_ * D_;
    int e = f / od;
    int rem = f - e * od;
    float4 a = *(const float4*)(ew + f);
    float4 b = *(const float4*)(sw + rem);
    ushort4 o;
    o.x = f2bf(a.x + b.x); o.y = f2bf(a.y + b.y);
    o.z = f2bf(a.z + b.z); o.w = f2bf(a.w + b.w);
    ((ushort4*)wb)[i] = o;
}

// ---------------- grouped GEMM: 128x128x64 tile, global_load_lds staging,
// fragment-contiguous LDS [kchunk][row][8] (conflict-free b128 reads) ----------------
#define BM 128
#define BN 128
#define BK 64

__global__ __launch_bounds__(256) void moe_gemm_kernel(
    const unsigned short* __restrict__ xb,   // [N_, D_] bf16
    const unsigned short* __restrict__ wb,   // [E_, O_, D_] bf16
    const float* __restrict__ expert_b,      // [E_, O_]
    const int* __restrict__ counts,
    const int* __restrict__ pair_token,
    const float* __restrict__ pair_gate,
    float* __restrict__ y)                   // [N_, O_]
{
    int e = blockIdx.z;
    int cnt = counts[e];
    int m0 = blockIdx.y * BM;
    if (m0 >= cnt) return;
    int n0 = blockIdx.x * BN;

    // [kch 0..7][row 0..127][8 bf16] = 16 KB each
    __shared__ __align__(16) unsigned short sA[(BK / 8) * BM * 8];
    __shared__ __align__(16) unsigned short sB[(BK / 8) * BN * 8];

    int tid  = threadIdx.x;
    int lane = tid & 63;
    int wid  = tid >> 6;
    int wm = wid & 1, wn = wid >> 1;
    int l16 = lane & 15;
    int quad = lane >> 4;

    // staging assignment: chunk c = tid (+256*s); row = tid&127, kch base = tid>>7
    int srow = tid & 127;
    int kchb = tid >> 7;
    int arow = m0 + srow; if (arow >= cnt) arow = cnt - 1;
    int stok = pair_token[e * N_ + arow];
    const unsigned short* ga = xb + (size_t)stok * D_;
    const unsigned short* gb = wb + ((size_t)e * O_ + n0 + srow) * D_;
    char* sAb = (char*)sA + wid * 1024;   // wave-uniform LDS base (wid*64 chunks *16B)
    char* sBb = (char*)sB + wid * 1024;

    f32x4 acc[4][4];
#pragma unroll
    for (int a = 0; a < 4; ++a)
#pragma unroll
        for (int b = 0; b < 4; ++b) acc[a][b] = (f32x4){0.f, 0.f, 0.f, 0.f};

    for (int k0 = 0; k0 < D_; k0 += BK) {
#pragma unroll
        for (int s = 0; s < 4; ++s) {
            int kch = kchb + 2 * s;
            async16(ga + k0 + kch * 8, sAb + s * 4096);
            async16(gb + k0 + kch * 8, sBb + s * 4096);
        }
        __syncthreads();   // drains vmcnt -> LDS tiles complete

#pragma unroll
        for (int ks = 0; ks < 2; ++ks) {
            int kch = ks * 4 + quad;
            bf16x8 af[4], bfr[4];
#pragma unroll
            for (int mi = 0; mi < 4; ++mi)
                af[mi] = *(const bf16x8*)&sA[(kch * BM + wm * 64 + mi * 16 + l16) * 8];
#pragma unroll
            for (int ni = 0; ni < 4; ++ni)
                bfr[ni] = *(const bf16x8*)&sB[(kch * BN + wn * 64 + ni * 16 + l16) * 8];
#pragma unroll
            for (int mi = 0; mi < 4; ++mi)
#pragma unroll
                for (int ni = 0; ni < 4; ++ni)
                    acc[mi][ni] = __builtin_amdgcn_mfma_f32_16x16x32_bf16(
                        af[mi], bfr[ni], acc[mi][ni], 0, 0, 0);
        }
        __syncthreads();
    }

    // epilogue: C/D map (16x16x32): col = lane&15, row = quad*4+reg  [verified]
    float bias[4];
#pragma unroll
    for (int ni = 0; ni < 4; ++ni)
        bias[ni] = expert_b[e * O_ + n0 + wn * 64 + ni * 16 + l16];
#pragma unroll
    for (int mi = 0; mi < 4; ++mi) {
        int rb = m0 + wm * 64 + mi * 16 + quad * 4;
#pragma unroll
        for (int reg = 0; reg < 4; ++reg) {
            int r = rb + reg;
            if (r < cnt) {
                int token  = pair_token[e * N_ + r];
                float gate = pair_gate[e * N_ + r];
#pragma unroll
                for (int ni = 0; ni < 4; ++ni) {
                    int o = n0 + wn * 64 + ni * 16 + l16;
                    atomicAdd(&y[(size_t)token * O_ + o],
                              gate * (acc[mi][ni][reg] + bias[ni]));
                }
            }
        }
    }
}

extern "C" void kernel_launch(void* const* d_in, const int* in_sizes, int n_in,
                              void* d_out, int out_size, void* d_ws, size_t ws_size,
                              hipStream_t stream) {
    const float* x        = (const float*)d_in[0];  // [4,512,768]
    const float* w_gate   = (const float*)d_in[1];  // [768,8]
    const float* expert_w = (const float*)d_in[2];  // [8,3072,768]
    const float* expert_b = (const float*)d_in[3];  // [8,3072]
    const float* static_w = (const float*)d_in[4];  // [3072,768]
    float* out = (float*)d_out;                     // y [N_,O_] then loss scalar

    char* ws = (char*)d_ws;
    int*   counts     = (int*)(ws + 0);
    int*   pair_token = (int*)(ws + 4096);
    float* pair_gate  = (float*)(ws + 4096 + 65536);
    int*   choice_e   = (int*)(ws + 4096 + 131072);
    float* choice_g   = (float*)(ws + 4096 + 131072 + 16384);
    unsigned short* xb = (unsigned short*)(ws + 4096 + 131072 + 32768);
    unsigned short* wb = (unsigned short*)(ws + 4096 + 131072 + 32768 + 3145728);

    gating_kernel<<<N_ / 4, 256, 0, stream>>>(x, w_gate, xb, choice_e, choice_g, out);
    compact_kernel<<<1, 1024, 0, stream>>>(choice_e, choice_g, counts,
                                           pair_token, pair_gate, out + (size_t)N_ * O_);
    prep_w_kernel<<<(E_ * O_ * D_ / 4) / 256, 256, 0, stream>>>(expert_w, static_w, wb);

    dim3 grid(O_ / BN, N_ / BM, E_);
    moe_gemm_kernel<<<grid, 256, 0, stream>>>(xb, wb, expert_b, counts,
                                              pair_token, pair_gate, out);
}

// Round 3
// 210.216 us; speedup vs baseline: 1.2610x; 1.1162x over previous
//
#include <hip/hip_runtime.h>
#include <hip/hip_bf16.h>
#include <stdint.h>

#define E_ 8
#define D_ 768
#define O_ 3072
#define N_ 2048   // B*S = 4*512

typedef __attribute__((ext_vector_type(8))) __bf16 bf16x8;
typedef __attribute__((ext_vector_type(4))) float f32x4;

// round-to-nearest-even fp32 -> bf16 bits
__device__ __forceinline__ unsigned short f2bf(float f) {
    union { float f; uint32_t u; } a; a.f = f;
    uint32_t u = a.u;
    uint32_t r = (u + 0x7fffu + ((u >> 16) & 1u)) >> 16;
    return (unsigned short)r;
}

__device__ __forceinline__ void async16(const void* g, void* l) {
    __builtin_amdgcn_global_load_lds(
        (const __attribute__((address_space(1))) void*)g,
        (__attribute__((address_space(3))) void*)l, 16, 0, 0);
}

// ---------------- fused prologue ----------------
// blocks [0,512):        gating (1 wave/token) + x->bf16 cast + y zeroing
// blocks [512,512+18432): Wb[e] = bf16(expert_w[e] + static_w)
__global__ __launch_bounds__(256) void prologue_kernel(
    const float* __restrict__ x, const float* __restrict__ w_gate,
    const float* __restrict__ ew, const float* __restrict__ sw,
    unsigned short* __restrict__ xb, unsigned short* __restrict__ wb,
    int* __restrict__ choice_e, float* __restrict__ choice_g,
    float* __restrict__ y)
{
    if (blockIdx.x >= 512) {
        // ---- prep_w ----
        int i = (blockIdx.x - 512) * 256 + threadIdx.x;   // float4 units
        int f = i * 4;
        const int od = O_ * D_;
        int e = f / od;
        int rem = f - e * od;
        float4 a = *(const float4*)(ew + f);
        float4 b = *(const float4*)(sw + rem);
        ushort4 o;
        o.x = f2bf(a.x + b.x); o.y = f2bf(a.y + b.y);
        o.z = f2bf(a.z + b.z); o.w = f2bf(a.w + b.w);
        ((ushort4*)wb)[i] = o;
        return;
    }

    // ---- gating ----
    int wid  = threadIdx.x >> 6;
    int lane = threadIdx.x & 63;
    int n = blockIdx.x * 4 + wid;
    const float* xr = x + (size_t)n * D_;

    float acc[E_];
#pragma unroll
    for (int e = 0; e < E_; ++e) acc[e] = 0.f;

    for (int c = 0; c < D_ / 64; ++c) {
        int d = c * 64 + lane;
        float xv = xr[d];
        xb[(size_t)n * D_ + d] = f2bf(xv);          // fused cast
        const float* wg = w_gate + (size_t)d * E_;
        float4 w0 = *(const float4*)(wg);
        float4 w1 = *(const float4*)(wg + 4);
        acc[0] += xv * w0.x; acc[1] += xv * w0.y;
        acc[2] += xv * w0.z; acc[3] += xv * w0.w;
        acc[4] += xv * w1.x; acc[5] += xv * w1.y;
        acc[6] += xv * w1.z; acc[7] += xv * w1.w;
    }
#pragma unroll
    for (int e = 0; e < E_; ++e) {
        float v = acc[e];
        for (int off = 32; off > 0; off >>= 1) v += __shfl_xor(v, off, 64);
        acc[e] = v;
    }
    if (lane == 0) {
        // top-2, lower index wins ties (matches lax.top_k)
        int i0 = 0; float v0 = acc[0];
#pragma unroll
        for (int e = 1; e < E_; ++e) if (acc[e] > v0) { v0 = acc[e]; i0 = e; }
        int i1 = -1; float v1 = -3.0e38f;
#pragma unroll
        for (int e = 0; e < E_; ++e) if (e != i0 && acc[e] > v1) { v1 = acc[e]; i1 = e; }
        float ex = expf(v1 - v0);
        float g0 = 1.f / (1.f + ex);
        float g1 = ex / (1.f + ex);
        choice_e[2 * n]     = i0;  choice_g[2 * n]     = g0;
        choice_e[2 * n + 1] = i1;  choice_g[2 * n + 1] = g1;
    }

    // fused y zeroing: 512 blocks x 12288 floats = N_*O_
    float4 z = {0.f, 0.f, 0.f, 0.f};
    float4* yb = (float4*)(y + (size_t)blockIdx.x * 12288);
#pragma unroll
    for (int i = 0; i < 12; ++i) yb[threadIdx.x + 256 * i] = z;
}

// ---------------- compact: per-expert lists + loss (1 block) ----------------
__global__ __launch_bounds__(1024) void compact_kernel(
    const int* __restrict__ choice_e, const float* __restrict__ choice_g,
    int* __restrict__ counts, int* __restrict__ pair_token,
    float* __restrict__ pair_gate, float* __restrict__ out_loss)
{
    __shared__ int   s_cnt[E_];
    __shared__ float s_imp[E_];
    int t = threadIdx.x;
    if (t < E_) { s_cnt[t] = 0; s_imp[t] = 0.f; }
    __syncthreads();
    for (int i = t; i < N_ * 2; i += 1024) {
        int e = choice_e[i];
        float gv = choice_g[i];
        int pos = atomicAdd(&s_cnt[e], 1);
        pair_token[e * N_ + pos] = i >> 1;
        pair_gate[e * N_ + pos]  = gv;
        atomicAdd(&s_imp[e], gv);
    }
    __syncthreads();
    if (t < E_) counts[t] = s_cnt[t];
    if (t == 0) {
        float mi = 0.f, ml = 0.f, imp[E_], ld[E_];
#pragma unroll
        for (int i = 0; i < E_; ++i) {
            imp[i] = s_imp[i]; ld[i] = (float)s_cnt[i];
            mi += imp[i]; ml += ld[i];
        }
        mi /= (float)E_; ml /= (float)E_;
        float vi = 0.f, vl = 0.f;
#pragma unroll
        for (int i = 0; i < E_; ++i) {
            vi += (imp[i] - mi) * (imp[i] - mi);
            vl += (ld[i] - ml) * (ld[i] - ml);
        }
        vi /= (float)(E_ - 1); vl /= (float)(E_ - 1);
        *out_loss = 0.01f * (vi / (mi * mi + 1e-10f) + vl / (ml * ml + 1e-10f));
    }
}

// ---------------- grouped GEMM: 128x128x64, global_load_lds staging ----------------
// LDS layout (16B chunks): chunk(row,kch) = row*8 + (kch ^ (row&7)).
// Staging lane l, step s: chunk c = tid+256s -> row=c>>3, fetches global
// kch = (c&7)^(row&7) -> each 8-lane group covers one contiguous 128B row
// segment (coalesced); MFMA reads land 2-per-bank-phase (free, m136).
#define BM 128
#define BN 128
#define BK 64

__global__ __launch_bounds__(256) void moe_gemm_kernel(
    const unsigned short* __restrict__ xb,   // [N_, D_] bf16
    const unsigned short* __restrict__ wb,   // [E_, O_, D_] bf16
    const float* __restrict__ expert_b,      // [E_, O_]
    const int* __restrict__ counts,
    const int* __restrict__ pair_token,
    const float* __restrict__ pair_gate,
    float* __restrict__ y)                   // [N_, O_]
{
    int e = blockIdx.z;
    int cnt = counts[e];
    int m0 = blockIdx.y * BM;
    if (m0 >= cnt) return;
    int n0 = blockIdx.x * BN;

    __shared__ __align__(16) unsigned short sA[BM * BK];   // 16 KB
    __shared__ __align__(16) unsigned short sB[BN * BK];   // 16 KB

    int tid  = threadIdx.x;
    int lane = tid & 63;
    int wid  = tid >> 6;
    int wm = wid & 1, wn = wid >> 1;
    int l16 = lane & 15;
    int quad = lane >> 4;

    // staging: rows r0+32s (s=0..3), fetched k-chunk kg constant across s
    int r0 = tid >> 3;                       // 0..31
    int kg = (tid & 7) ^ (r0 & 7);
    const unsigned short* gA[4];
    const unsigned short* gB[4];
#pragma unroll
    for (int s = 0; s < 4; ++s) {
        int row = r0 + 32 * s;
        int ar = m0 + row; if (ar >= cnt) ar = cnt - 1;
        gA[s] = xb + (size_t)pair_token[e * N_ + ar] * D_ + kg * 8;
        gB[s] = wb + ((size_t)e * O_ + n0 + row) * D_ + kg * 8;
    }
    char* lA = (char*)sA + wid * 1024;       // wave-uniform LDS base
    char* lB = (char*)sB + wid * 1024;

    f32x4 acc[4][4];
#pragma unroll
    for (int a = 0; a < 4; ++a)
#pragma unroll
        for (int b = 0; b < 4; ++b) acc[a][b] = (f32x4){0.f, 0.f, 0.f, 0.f};

    for (int k0 = 0; k0 < D_; k0 += BK) {
#pragma unroll
        for (int s = 0; s < 4; ++s) {
            async16(gA[s] + k0, lA + s * 4096);
            async16(gB[s] + k0, lB + s * 4096);
        }
        __syncthreads();   // drains vmcnt -> tiles complete

#pragma unroll
        for (int ks = 0; ks < 2; ++ks) {
            bf16x8 af[4], bfr[4];
#pragma unroll
            for (int mi = 0; mi < 4; ++mi) {
                int row = wm * 64 + mi * 16 + l16;
                int ch  = row * 8 + ((ks * 4 + quad) ^ (row & 7));
                af[mi] = *(const bf16x8*)&sA[ch * 8];
            }
#pragma unroll
            for (int ni = 0; ni < 4; ++ni) {
                int row = wn * 64 + ni * 16 + l16;
                int ch  = row * 8 + ((ks * 4 + quad) ^ (row & 7));
                bfr[ni] = *(const bf16x8*)&sB[ch * 8];
            }
#pragma unroll
            for (int mi = 0; mi < 4; ++mi)
#pragma unroll
                for (int ni = 0; ni < 4; ++ni)
                    acc[mi][ni] = __builtin_amdgcn_mfma_f32_16x16x32_bf16(
                        af[mi], bfr[ni], acc[mi][ni], 0, 0, 0);
        }
        __syncthreads();
    }

    // epilogue: C/D map (16x16x32): col = lane&15, row = quad*4+reg  [verified]
    float bias[4];
#pragma unroll
    for (int ni = 0; ni < 4; ++ni)
        bias[ni] = expert_b[e * O_ + n0 + wn * 64 + ni * 16 + l16];
#pragma unroll
    for (int mi = 0; mi < 4; ++mi) {
        int rb = m0 + wm * 64 + mi * 16 + quad * 4;
#pragma unroll
        for (int reg = 0; reg < 4; ++reg) {
            int r = rb + reg;
            if (r < cnt) {
                int token  = pair_token[e * N_ + r];
                float gate = pair_gate[e * N_ + r];
#pragma unroll
                for (int ni = 0; ni < 4; ++ni) {
                    int o = n0 + wn * 64 + ni * 16 + l16;
                    atomicAdd(&y[(size_t)token * O_ + o],
                              gate * (acc[mi][ni][reg] + bias[ni]));
                }
            }
        }
    }
}

extern "C" void kernel_launch(void* const* d_in, const int* in_sizes, int n_in,
                              void* d_out, int out_size, void* d_ws, size_t ws_size,
                              hipStream_t stream) {
    const float* x        = (const float*)d_in[0];  // [4,512,768]
    const float* w_gate   = (const float*)d_in[1];  // [768,8]
    const float* expert_w = (const float*)d_in[2];  // [8,3072,768]
    const float* expert_b = (const float*)d_in[3];  // [8,3072]
    const float* static_w = (const float*)d_in[4];  // [3072,768]
    float* out = (float*)d_out;                     // y [N_,O_] then loss scalar

    char* ws = (char*)d_ws;
    int*   counts     = (int*)(ws + 0);
    int*   pair_token = (int*)(ws + 4096);
    float* pair_gate  = (float*)(ws + 4096 + 65536);
    int*   choice_e   = (int*)(ws + 4096 + 131072);
    float* choice_g   = (float*)(ws + 4096 + 131072 + 16384);
    unsigned short* xb = (unsigned short*)(ws + 4096 + 131072 + 32768);
    unsigned short* wb = (unsigned short*)(ws + 4096 + 131072 + 32768 + 3145728);

    prologue_kernel<<<512 + (E_ * O_ * D_ / 4) / 256, 256, 0, stream>>>(
        x, w_gate, expert_w, static_w, xb, wb, choice_e, choice_g, out);
    compact_kernel<<<1, 1024, 0, stream>>>(choice_e, choice_g, counts,
                                           pair_token, pair_gate, out + (size_t)N_ * O_);

    dim3 grid(O_ / BN, N_ / BM, E_);
    moe_gemm_kernel<<<grid, 256, 0, stream>>>(xb, wb, expert_b, counts,
                                              pair_token, pair_gate, out);
}